// Round 20
// baseline (93.948 us; speedup 1.0000x reference)
//
#include <hip/hip_runtime.h>
#include <hip/hip_fp16.h>

// ---- problem constants ----
#define KW 11
#define NB 2            // N * C
#define DI 96
#define HI 256
#define WI 256
#define DOUT 86
#define HOUT 246
#define WOUT 246
#define HT 16           // output tile height
#define WT 16           // output tile width
#define DCH 4           // chunks along D: dpc = 22,22,22,20 (all-even slices)
#define RR 26           // HT + KW - 1 region rows
#define HSZ (HI * WI)
#define SSIM_C1 1e-4f
#define SSIM_C2 9e-4f
#define NBLK (16 * 16 * NB * DCH)   // 2048 = exactly 8 blocks/CU
// raw pair layout: [img1: 2sl x 26r x 7c = 364 slots][img2: 364 slots] x 16B
// = 11648 B. Row stride 7 slots (odd) -> chunk bank-group (c - r) mod 8
// uniform. One u32 byte-offset per task serves BOTH images.
#define RAW1_SLOT 364
#define RAW_SLOT 728

typedef const unsigned int __attribute__((address_space(1)))* gp1_t;
typedef unsigned int __attribute__((address_space(3)))* lp3_t;
using f32x2 = __attribute__((ext_vector_type(2))) float;
using f32x4 = __attribute__((ext_vector_type(4))) float;

__device__ __forceinline__ void gl_lds16(const float* g, float* l) {
    __builtin_amdgcn_global_load_lds((gp1_t)(const void*)g, (lp3_t)(void*)l, 16, 0, 0);
}

// packed fp32 FMA, wave-uniform weight in SGPR pair.
__device__ __forceinline__ f32x2 pk_fma_s(f32x2 w, f32x2 x, f32x2 acc) {
    f32x2 d;
    asm("v_pk_fma_f32 %0, %1, %2, %3" : "=v"(d) : "s"(w), "v"(x), "v"(acc));
    return d;
}

// packed fp16 FMA (2 fields per op), wave-uniform weight in SGPR.
__device__ __forceinline__ unsigned pk_fma_h(unsigned w, unsigned x, unsigned acc) {
    unsigned d;
    asm("v_pk_fma_f16 %0, %1, %2, %3" : "=v"(d) : "s"(w), "v"(x), "v"(acc));
    return d;
}

// pack 2 f32 -> 2 fp16 (RTZ; bias negligible on centered data)
__device__ __forceinline__ unsigned pkrtz(float a, float b) {
    auto h = __builtin_amdgcn_cvt_pkrtz(a, b);
    return __builtin_bit_cast(unsigned, h);
}

// unpack 2 fp16 -> f32x2
__device__ __forceinline__ f32x2 h2f(unsigned u) {
    f32x2 r;
    r.x = __half2float(__ushort_as_half((unsigned short)(u & 0xffffu)));
    r.y = __half2float(__ushort_as_half((unsigned short)(u >> 16)));
    return r;
}

__device__ __forceinline__ float rfl(float x) {
    return __int_as_float(__builtin_amdgcn_readfirstlane(__float_as_int(x)));
}

// fp16 packed ring-buffer D-conv step, compile-time slot indices.
template<int J>
__device__ __forceinline__ void acc_step_h(
    unsigned (&AB)[KW], unsigned (&PQ)[KW], const unsigned (&wh)[KW],
    unsigned f12, unsigned f34, bool emit, unsigned& o12, unsigned& o34)
{
    #pragma unroll
    for (int p = 0; p < KW; ++p) {
        const int s = (J - p + KW) % KW;   // compile-time
        AB[s] = pk_fma_h(wh[p], f12, AB[s]);
        PQ[s] = pk_fma_h(wh[p], f34, PQ[s]);
    }
    const int C = (J + 1) % KW;
    if (emit) { o12 = AB[C]; o34 = PQ[C]; }
    AB[C] = 0u;
    PQ[C] = 0u;
}

// R20 = R15 verbatim + DCH=4. R15's resources (VGPR 44 < 64-cliff, LDS
// 18.9 KB) permit 8 blocks/CU but its DCH=3 grid supplied only 6; DCH=4
// (grid 2048) fills all 8 residency slots (+33% waves/CU) at +8.6% D-halo
// slice-work. R19's counted-vmcnt pipeline was correctness-fixed but
// neutral (92.9 vs 90.3) at 5 blocks/CU -> abandoned; stall is absorbed
// by TLP, not by barrier engineering.
// NUMERICS: identical to R15 (absmax 0.0): centered inputs, f32 W-conv,
// fp16 H-conv + D-ring, f32 SSIM + mean.
static __global__ __launch_bounds__(256, 2) void ssim_main(
    const float* __restrict__ img1, const float* __restrict__ img2,
    const float* __restrict__ win, float* __restrict__ bsum)
{
    __shared__ __align__(16) float rawf[RAW_SLOT * 4];    // 11648 B
    // A4H[r][c][sl]: uint2 = {pk16(s1,s2), pk16(s3,s4)}; 26*17*2*8 = 7072 B.
    __shared__ __align__(16) uint2 a4h[RR][17][2];
    float* const tmpw = (float*)a4h;            // aliased scratch (121 floats)
    float* const w1s  = (float*)a4h + 128;      // 11 floats
    float* const red  = (float*)a4h + 140;      // 4 floats (post-loop only)

    const int t = threadIdx.x;
    const int bz = blockIdx.z;            // n*4 + chunk
    const int n = bz >> 2, chunk = bz & 3;
    const int d0 = chunk * 22;
    const int dpc = (chunk == 3) ? 20 : 22;
    const int NIT = (dpc + KW - 1) >> 1;   // pairs: 16,16,16,15 (slices even)
    const int h0 = blockIdx.y * HT, w0 = blockIdx.x * WT;

    // 1-D separable profile from marginal sums of the 3-D window.
    if (t < 121) {
        const int i = t / KW, j = t - i * KW;
        const float* wp = win + i * (KW * KW) + j * KW;
        float s = 0.f;
        #pragma unroll
        for (int m = 0; m < KW; ++m) s += wp[m];
        tmpw[t] = s;
    }
    __syncthreads();
    if (t < KW) {
        float s = 0.f;
        #pragma unroll
        for (int j = 0; j < KW; ++j) s += tmpw[t * KW + j];
        w1s[t] = s;
    }
    __syncthreads();
    f32x2 w2[KW];                          // f32 pairs (SGPR; phase A)
    unsigned whq[KW];                      // fp16x2 packed (SGPR; phase B + ring)
    #pragma unroll
    for (int k = 0; k < KW; ++k) {
        const float ws = rfl(w1s[k]);
        w2[k] = (f32x2){ws, ws};
        const unsigned hb = (unsigned)__half_as_ushort(__float2half(ws));  // RNE
        whq[k] = __builtin_amdgcn_readfirstlane(hb | (hb << 16));
    }
    __syncthreads();   // w-scratch region of a4h free before phase A writes

    // ---- staging: one u32 byte-offset per dual-task (img1 AND img2) ----
    unsigned soff[2];
    #pragma unroll
    for (int q = 0; q < 2; ++q) {
        const int s = t + 256 * q;
        const int sl = (s >= 182) ? 1 : 0;
        const int v = (s < RAW1_SLOT ? s : 0) - sl * 182;
        const int r = v / 7;
        const int c = v - 7 * r;
        const int gh = h0 + r, gw0 = w0 + 4 * c;
        const bool oob = (s >= RAW1_SLOT) || (gh >= HI) || (gw0 >= WI);
        soff[q] = oob ? 0u
                      : (unsigned)((((n * DI + d0 + sl) * HSZ) + gh * WI + gw0) * 4);
    }
    // OOB tasks walk img1[0 + k*2MB] (max ~34MB < 50.3MB buffer: in-bounds
    // garbage) and only ever feed `valid`-masked outputs.
    #define STAGE() do { \
        gl_lds16((const float*)((const char*)img1 + soff[0]), &rawf[4 * t]); \
        gl_lds16((const float*)((const char*)img2 + soff[0]), &rawf[RAW1_SLOT * 4 + 4 * t]); \
        if (t < RAW1_SLOT - 256) { \
            gl_lds16((const float*)((const char*)img1 + soff[1]), &rawf[1024 + 4 * t]); \
            gl_lds16((const float*)((const char*)img2 + soff[1]), &rawf[RAW1_SLOT * 4 + 1024 + 4 * t]); \
        } \
        soff[0] += 8 * HSZ; soff[1] += 8 * HSZ; \
    } while (0)

    // fp16 packed D-conv rings (22 VGPRs total).
    unsigned rABh[KW], rPQh[KW];
    #pragma unroll
    for (int p = 0; p < KW; ++p) { rABh[p] = 0u; rPQh[p] = 0u; }

    const int ty = t >> 4, tx = t & 15;
    const bool valid = (h0 + ty < HOUT) && (w0 + tx < WOUT);
    float partial = 0.f;

    // ---- phase-A per-thread decode, ROW-FASTEST, hoisted (t < 208) ----
    const int paSl = (t >= 104) ? 1 : 0;
    const int paV  = (t < 208 ? t : 0) - paSl * 104;
    const int paCg = paV / 26;
    const int paR  = paV - paCg * 26;
    const float* const paA = &rawf[(paSl * 182 + paR * 7) * 4];   // img1 row
    const float* const paB = paA + RAW1_SLOT * 4;                 // img2 row
    uint2* const paW = &a4h[paR][4 * paCg][paSl];   // +2 uint2 per output o

    auto phaseA = [&]() {
        f32x2 s12[4] = {{0.f,0.f},{0.f,0.f},{0.f,0.f},{0.f,0.f}};
        f32x2 s34[4] = {{0.f,0.f},{0.f,0.f},{0.f,0.f},{0.f,0.f}};
        #pragma unroll
        for (int q = 0; q < 4; ++q) {
            const f32x4 aq = *(const f32x4*)(paA + 4 * (paCg + q));   // img1
            const f32x4 bq = *(const f32x4*)(paB + 4 * (paCg + q));   // img2
            #pragma unroll
            for (int j = 0; j < 4; ++j) {
                const int m = 4 * q + j;                 // rel col
                if (m < 14) {
                    f32x2 pxy = (f32x2){aq[j], bq[j]};
                    pxy += (f32x2){-0.5f, -0.5f};        // center
                    const float x = pxy.x, y = pxy.y;
                    const f32x2 pts = (f32x2){x * y, fmaf(x, x, y * y)};
                    #pragma unroll
                    for (int o = 0; o < 4; ++o) {
                        const int k = m - o;             // compile-time
                        if (k >= 0 && k <= 10) {
                            s12[o] = pk_fma_s(w2[k], pxy, s12[o]);
                            s34[o] = pk_fma_s(w2[k], pts, s34[o]);
                        }
                    }
                }
            }
        }
        #pragma unroll
        for (int o = 0; o < 4; ++o)
            paW[2 * o] = make_uint2(pkrtz(s12[o].x, s12[o].y),
                                    pkrtz(s34[o].x, s34[o].y));
    };

    // ---- prologue: stage slices d0, d0+1 ----
    STAGE();
    __syncthreads();   // drains vmcnt -> raw ready

    int jj = 0;        // (2i) % 11
    for (int i = 0; i < NIT; ++i) {
        // ---- phase A: both slices' W-convs (208 tasks) ----
        if (t < 208) phaseA();
        __syncthreads();   // A4H ready; raw fully consumed

        // ---- issue staging for next slice pair (lands during phase B) ----
        if (i + 1 < NIT) STAGE();

        // ---- phase B: fp16 H-conv, both slices in one uint4/tap ----
        unsigned ha12 = 0u, ha34 = 0u, hb12 = 0u, hb34 = 0u;
        #pragma unroll
        for (int kh = 0; kh < KW; ++kh) {
            const uint4 v = *(const uint4*)&a4h[ty + kh][tx][0];
            ha12 = pk_fma_h(whq[kh], v.x, ha12);
            ha34 = pk_fma_h(whq[kh], v.y, ha34);
            hb12 = pk_fma_h(whq[kh], v.z, hb12);
            hb34 = pk_fma_h(whq[kh], v.w, hb34);
        }

        const bool emit = (i >= 5);
        unsigned oa12u = 0u, oa34u = 0u, ob12u = 0u, ob34u = 0u;
        switch (jj) {
            #define CASE2(J) case J: \
                acc_step_h<J>(rABh, rPQh, whq, ha12, ha34, emit, oa12u, oa34u); \
                acc_step_h<(J+1)%KW>(rABh, rPQh, whq, hb12, hb34, emit, ob12u, ob34u); \
                break;
            CASE2(0) CASE2(1) CASE2(2) CASE2(3) CASE2(4) CASE2(5)
            CASE2(6) CASE2(7) CASE2(8) CASE2(9) CASE2(10)
            #undef CASE2
        }
        jj += 2; if (jj >= KW) jj -= KW;

        if (emit && valid) {
            // centered: mu = 0.5 + a; sigma12 = E12' - a*b; ssum = Ess' - a^2 - b^2
            {
                const f32x2 v12 = h2f(oa12u), v34 = h2f(oa34u);
                const float a = v12.x, b = v12.y;
                const float mu1 = a + 0.5f, mu2 = b + 0.5f;
                const float m11 = mu1 * mu1, m22 = mu2 * mu2, m12 = mu1 * mu2;
                const float s12c = v34.x - a * b;
                const float ssum = v34.y - a * a - b * b;
                const float num = (2.f * m12 + SSIM_C1) * (2.f * s12c + SSIM_C2);
                const float den = (m11 + m22 + SSIM_C1) * (ssum + SSIM_C2);
                partial += num * __builtin_amdgcn_rcpf(den);
            }
            {
                const f32x2 v12 = h2f(ob12u), v34 = h2f(ob34u);
                const float a = v12.x, b = v12.y;
                const float mu1 = a + 0.5f, mu2 = b + 0.5f;
                const float m11 = mu1 * mu1, m22 = mu2 * mu2, m12 = mu1 * mu2;
                const float s12c = v34.x - a * b;
                const float ssum = v34.y - a * a - b * b;
                const float num = (2.f * m12 + SSIM_C1) * (2.f * s12c + SSIM_C2);
                const float den = (m11 + m22 + SSIM_C1) * (ssum + SSIM_C2);
                partial += num * __builtin_amdgcn_rcpf(den);
            }
        }
        __syncthreads();   // staged raw complete + A4H consumed
    }

    // ---- block reduction (red aliases a4h; A4H dead after final barrier) ----
    #pragma unroll
    for (int off = 32; off >= 1; off >>= 1)
        partial += __shfl_down(partial, off, 64);
    if ((t & 63) == 0) red[t >> 6] = partial;
    __syncthreads();
    if (t == 0) {
        bsum[(blockIdx.z * gridDim.y + blockIdx.y) * gridDim.x + blockIdx.x]
            = red[0] + red[1] + red[2] + red[3];
    }
}

static __global__ __launch_bounds__(256) void ssim_reduce(
    const float* __restrict__ bsum, float* __restrict__ out)
{
    __shared__ double red[4];
    const int t = threadIdx.x;
    double s = 0.0;
    for (int i = t; i < NBLK; i += 256) s += (double)bsum[i];
    #pragma unroll
    for (int off = 32; off >= 1; off >>= 1)
        s += __shfl_down(s, off, 64);
    if ((t & 63) == 0) red[t >> 6] = s;
    __syncthreads();
    if (t == 0) {
        const double tot = red[0] + red[1] + red[2] + red[3];
        out[0] = (float)(tot / (double)((long)NB * DOUT * HOUT * WOUT));
    }
}

extern "C" void kernel_launch(void* const* d_in, const int* in_sizes, int n_in,
                              void* d_out, int out_size, void* d_ws, size_t ws_size,
                              hipStream_t stream)
{
    const float* img1 = (const float*)d_in[0];
    const float* img2 = (const float*)d_in[1];
    const float* win  = (const float*)d_in[2];
    float* out  = (float*)d_out;
    float* bsum = (float*)d_ws;   // 2048 floats = 8 KB scratch

    dim3 grid(16, 16, NB * DCH);
    ssim_main<<<grid, 256, 0, stream>>>(img1, img2, win, bsum);
    ssim_reduce<<<1, 256, 0, stream>>>(bsum, out);
}

// Round 21
// 90.976 us; speedup vs baseline: 1.0327x; 1.0327x over previous
//
#include <hip/hip_runtime.h>
#include <hip/hip_fp16.h>

// ---- problem constants ----
#define KW 11
#define NB 2            // N * C
#define DI 96
#define HI 256
#define WI 256
#define DOUT 86
#define HOUT 246
#define WOUT 246
#define HT 16           // output tile height
#define WT 16           // output tile width
#define DCH 3           // chunks along D: dpc = 30,28,28 (all-even slice counts)
#define RR 26           // HT + KW - 1 region rows
#define HSZ (HI * WI)
#define SSIM_C1 1e-4f
#define SSIM_C2 9e-4f
#define NBLK (16 * 16 * NB * DCH)   // 1536 = 8 XCDs x 192 (exact -> bijective)
// raw pair layout: [img1: 2sl x 26r x 7c = 364 slots][img2: 364 slots] x 16B
// = 11648 B. Row stride 7 slots (odd) -> chunk bank-group (c - r) mod 8
// uniform. One u32 byte-offset per task serves BOTH images.
#define RAW1_SLOT 364
#define RAW_SLOT 728

typedef const unsigned int __attribute__((address_space(1)))* gp1_t;
typedef unsigned int __attribute__((address_space(3)))* lp3_t;
using f32x2 = __attribute__((ext_vector_type(2))) float;
using f32x4 = __attribute__((ext_vector_type(4))) float;

__device__ __forceinline__ void gl_lds16(const float* g, float* l) {
    __builtin_amdgcn_global_load_lds((gp1_t)(const void*)g, (lp3_t)(void*)l, 16, 0, 0);
}

// packed fp32 FMA, wave-uniform weight in SGPR pair.
__device__ __forceinline__ f32x2 pk_fma_s(f32x2 w, f32x2 x, f32x2 acc) {
    f32x2 d;
    asm("v_pk_fma_f32 %0, %1, %2, %3" : "=v"(d) : "s"(w), "v"(x), "v"(acc));
    return d;
}

// packed fp16 FMA (2 fields per op), wave-uniform weight in SGPR.
__device__ __forceinline__ unsigned pk_fma_h(unsigned w, unsigned x, unsigned acc) {
    unsigned d;
    asm("v_pk_fma_f16 %0, %1, %2, %3" : "=v"(d) : "s"(w), "v"(x), "v"(acc));
    return d;
}

// pack 2 f32 -> 2 fp16 (RTZ; bias negligible on centered data)
__device__ __forceinline__ unsigned pkrtz(float a, float b) {
    auto h = __builtin_amdgcn_cvt_pkrtz(a, b);
    return __builtin_bit_cast(unsigned, h);
}

// unpack 2 fp16 -> f32x2
__device__ __forceinline__ f32x2 h2f(unsigned u) {
    f32x2 r;
    r.x = __half2float(__ushort_as_half((unsigned short)(u & 0xffffu)));
    r.y = __half2float(__ushort_as_half((unsigned short)(u >> 16)));
    return r;
}

__device__ __forceinline__ float rfl(float x) {
    return __int_as_float(__builtin_amdgcn_readfirstlane(__float_as_int(x)));
}

// fp16 packed ring-buffer D-conv step, compile-time slot indices.
template<int J>
__device__ __forceinline__ void acc_step_h(
    unsigned (&AB)[KW], unsigned (&PQ)[KW], const unsigned (&wh)[KW],
    unsigned f12, unsigned f34, bool emit, unsigned& o12, unsigned& o34)
{
    #pragma unroll
    for (int p = 0; p < KW; ++p) {
        const int s = (J - p + KW) % KW;   // compile-time
        AB[s] = pk_fma_h(wh[p], f12, AB[s]);
        PQ[s] = pk_fma_h(wh[p], f34, PQ[s]);
    }
    const int C = (J + 1) % KW;
    if (emit) { o12 = AB[C]; o34 = PQ[C]; }
    AB[C] = 0u;
    PQ[C] = 0u;
}

// R21 = R15 (best, 90.3us) + bijective XCD-chunk block swizzle (T1/m204).
// Default dispatch round-robins consecutive blocks over 8 XCDs, scattering
// the 16 x-neighbors of a (y,z) row-band (which share 26 global rows every
// slice-step) across all 8 private L2s -> 8x duplicate halo fetch. With
// nwg = 1536 = 8*192 exactly, XCD k gets semantic range [192k,192k+192)
// = one contiguous (z, y-band) slab (~0.8 MB/step working set << 4 MB L2).
// Pure index permutation: correctness unaffected.
// NUMERICS: identical to R15 (absmax 0.0): centered inputs, f32 W-conv,
// fp16 H-conv + D-ring, f32 SSIM + mean.
static __global__ __launch_bounds__(256, 2) void ssim_main(
    const float* __restrict__ img1, const float* __restrict__ img2,
    const float* __restrict__ win, float* __restrict__ bsum)
{
    __shared__ __align__(16) float rawf[RAW_SLOT * 4];    // 11648 B
    // A4H[r][c][sl]: uint2 = {pk16(s1,s2), pk16(s3,s4)}; 26*17*2*8 = 7072 B.
    __shared__ __align__(16) uint2 a4h[RR][17][2];
    float* const tmpw = (float*)a4h;            // aliased scratch (121 floats)
    float* const w1s  = (float*)a4h + 128;      // 11 floats
    float* const red  = (float*)a4h + 140;      // 4 floats (post-loop only)

    const int t = threadIdx.x;
    // ---- bijective XCD-chunk swizzle: dispatch id -> semantic id ----
    const int orig = blockIdx.x + 16 * (blockIdx.y + 16 * blockIdx.z);
    const int sem  = (orig & 7) * (NBLK / 8) + (orig >> 3);   // XCD k -> [192k,192k+192)
    const int bx = sem & 15, by = (sem >> 4) & 15, bz = sem >> 8;

    const int n = (bz >= DCH) ? 1 : 0;
    const int chunk = bz - n * DCH;
    const int d0 = (chunk == 0) ? 0 : (chunk == 1 ? 30 : 58);
    const int dpc = (chunk == 0) ? 30 : 28;
    const int NIT = (dpc + KW - 1) >> 1;   // pairs: 20 or 19
    const int h0 = by * HT, w0 = bx * WT;

    // 1-D separable profile from marginal sums of the 3-D window.
    if (t < 121) {
        const int i = t / KW, j = t - i * KW;
        const float* wp = win + i * (KW * KW) + j * KW;
        float s = 0.f;
        #pragma unroll
        for (int m = 0; m < KW; ++m) s += wp[m];
        tmpw[t] = s;
    }
    __syncthreads();
    if (t < KW) {
        float s = 0.f;
        #pragma unroll
        for (int j = 0; j < KW; ++j) s += tmpw[t * KW + j];
        w1s[t] = s;
    }
    __syncthreads();
    f32x2 w2[KW];                          // f32 pairs (SGPR; phase A)
    unsigned whq[KW];                      // fp16x2 packed (SGPR; phase B + ring)
    #pragma unroll
    for (int k = 0; k < KW; ++k) {
        const float ws = rfl(w1s[k]);
        w2[k] = (f32x2){ws, ws};
        const unsigned hb = (unsigned)__half_as_ushort(__float2half(ws));  // RNE
        whq[k] = __builtin_amdgcn_readfirstlane(hb | (hb << 16));
    }
    __syncthreads();   // w-scratch region of a4h free before phase A writes

    // ---- staging: one u32 byte-offset per dual-task (img1 AND img2) ----
    unsigned soff[2];
    #pragma unroll
    for (int q = 0; q < 2; ++q) {
        const int s = t + 256 * q;
        const int sl = (s >= 182) ? 1 : 0;
        const int v = (s < RAW1_SLOT ? s : 0) - sl * 182;
        const int r = v / 7;
        const int c = v - 7 * r;
        const int gh = h0 + r, gw0 = w0 + 4 * c;
        const bool oob = (s >= RAW1_SLOT) || (gh >= HI) || (gw0 >= WI);
        soff[q] = oob ? 0u
                      : (unsigned)((((n * DI + d0 + sl) * HSZ) + gh * WI + gw0) * 4);
    }
    // OOB tasks walk img1[0 + k*2MB] (max ~32MB < 50.3MB buffer: in-bounds
    // garbage) and only ever feed `valid`-masked outputs.
    #define STAGE() do { \
        gl_lds16((const float*)((const char*)img1 + soff[0]), &rawf[4 * t]); \
        gl_lds16((const float*)((const char*)img2 + soff[0]), &rawf[RAW1_SLOT * 4 + 4 * t]); \
        if (t < RAW1_SLOT - 256) { \
            gl_lds16((const float*)((const char*)img1 + soff[1]), &rawf[1024 + 4 * t]); \
            gl_lds16((const float*)((const char*)img2 + soff[1]), &rawf[RAW1_SLOT * 4 + 1024 + 4 * t]); \
        } \
        soff[0] += 8 * HSZ; soff[1] += 8 * HSZ; \
    } while (0)

    // fp16 packed D-conv rings (22 VGPRs total).
    unsigned rABh[KW], rPQh[KW];
    #pragma unroll
    for (int p = 0; p < KW; ++p) { rABh[p] = 0u; rPQh[p] = 0u; }

    const int ty = t >> 4, tx = t & 15;
    const bool valid = (h0 + ty < HOUT) && (w0 + tx < WOUT);
    float partial = 0.f;

    // ---- phase-A per-thread decode, ROW-FASTEST, hoisted (t < 208) ----
    const int paSl = (t >= 104) ? 1 : 0;
    const int paV  = (t < 208 ? t : 0) - paSl * 104;
    const int paCg = paV / 26;
    const int paR  = paV - paCg * 26;
    const float* const paA = &rawf[(paSl * 182 + paR * 7) * 4];   // img1 row
    const float* const paB = paA + RAW1_SLOT * 4;                 // img2 row
    uint2* const paW = &a4h[paR][4 * paCg][paSl];   // +2 uint2 per output o

    auto phaseA = [&]() {
        f32x2 s12[4] = {{0.f,0.f},{0.f,0.f},{0.f,0.f},{0.f,0.f}};
        f32x2 s34[4] = {{0.f,0.f},{0.f,0.f},{0.f,0.f},{0.f,0.f}};
        #pragma unroll
        for (int q = 0; q < 4; ++q) {
            const f32x4 aq = *(const f32x4*)(paA + 4 * (paCg + q));   // img1
            const f32x4 bq = *(const f32x4*)(paB + 4 * (paCg + q));   // img2
            #pragma unroll
            for (int j = 0; j < 4; ++j) {
                const int m = 4 * q + j;                 // rel col
                if (m < 14) {
                    f32x2 pxy = (f32x2){aq[j], bq[j]};
                    pxy += (f32x2){-0.5f, -0.5f};        // center
                    const float x = pxy.x, y = pxy.y;
                    const f32x2 pts = (f32x2){x * y, fmaf(x, x, y * y)};
                    #pragma unroll
                    for (int o = 0; o < 4; ++o) {
                        const int k = m - o;             // compile-time
                        if (k >= 0 && k <= 10) {
                            s12[o] = pk_fma_s(w2[k], pxy, s12[o]);
                            s34[o] = pk_fma_s(w2[k], pts, s34[o]);
                        }
                    }
                }
            }
        }
        #pragma unroll
        for (int o = 0; o < 4; ++o)
            paW[2 * o] = make_uint2(pkrtz(s12[o].x, s12[o].y),
                                    pkrtz(s34[o].x, s34[o].y));
    };

    // ---- prologue: stage slices d0, d0+1 ----
    STAGE();
    __syncthreads();   // drains vmcnt -> raw ready

    int jj = 0;        // (2i) % 11
    for (int i = 0; i < NIT; ++i) {
        // ---- phase A: both slices' W-convs (208 tasks) ----
        if (t < 208) phaseA();
        __syncthreads();   // A4H ready; raw fully consumed

        // ---- issue staging for next slice pair (lands during phase B) ----
        if (i + 1 < NIT) STAGE();

        // ---- phase B: fp16 H-conv, both slices in one uint4/tap ----
        unsigned ha12 = 0u, ha34 = 0u, hb12 = 0u, hb34 = 0u;
        #pragma unroll
        for (int kh = 0; kh < KW; ++kh) {
            const uint4 v = *(const uint4*)&a4h[ty + kh][tx][0];
            ha12 = pk_fma_h(whq[kh], v.x, ha12);
            ha34 = pk_fma_h(whq[kh], v.y, ha34);
            hb12 = pk_fma_h(whq[kh], v.z, hb12);
            hb34 = pk_fma_h(whq[kh], v.w, hb34);
        }

        const bool emit = (i >= 5);
        unsigned oa12u = 0u, oa34u = 0u, ob12u = 0u, ob34u = 0u;
        switch (jj) {
            #define CASE2(J) case J: \
                acc_step_h<J>(rABh, rPQh, whq, ha12, ha34, emit, oa12u, oa34u); \
                acc_step_h<(J+1)%KW>(rABh, rPQh, whq, hb12, hb34, emit, ob12u, ob34u); \
                break;
            CASE2(0) CASE2(1) CASE2(2) CASE2(3) CASE2(4) CASE2(5)
            CASE2(6) CASE2(7) CASE2(8) CASE2(9) CASE2(10)
            #undef CASE2
        }
        jj += 2; if (jj >= KW) jj -= KW;

        if (emit && valid) {
            // centered: mu = 0.5 + a; sigma12 = E12' - a*b; ssum = Ess' - a^2 - b^2
            {
                const f32x2 v12 = h2f(oa12u), v34 = h2f(oa34u);
                const float a = v12.x, b = v12.y;
                const float mu1 = a + 0.5f, mu2 = b + 0.5f;
                const float m11 = mu1 * mu1, m22 = mu2 * mu2, m12 = mu1 * mu2;
                const float s12c = v34.x - a * b;
                const float ssum = v34.y - a * a - b * b;
                const float num = (2.f * m12 + SSIM_C1) * (2.f * s12c + SSIM_C2);
                const float den = (m11 + m22 + SSIM_C1) * (ssum + SSIM_C2);
                partial += num * __builtin_amdgcn_rcpf(den);
            }
            {
                const f32x2 v12 = h2f(ob12u), v34 = h2f(ob34u);
                const float a = v12.x, b = v12.y;
                const float mu1 = a + 0.5f, mu2 = b + 0.5f;
                const float m11 = mu1 * mu1, m22 = mu2 * mu2, m12 = mu1 * mu2;
                const float s12c = v34.x - a * b;
                const float ssum = v34.y - a * a - b * b;
                const float num = (2.f * m12 + SSIM_C1) * (2.f * s12c + SSIM_C2);
                const float den = (m11 + m22 + SSIM_C1) * (ssum + SSIM_C2);
                partial += num * __builtin_amdgcn_rcpf(den);
            }
        }
        __syncthreads();   // staged raw complete + A4H consumed
    }

    // ---- block reduction (red aliases a4h; A4H dead after final barrier) ----
    #pragma unroll
    for (int off = 32; off >= 1; off >>= 1)
        partial += __shfl_down(partial, off, 64);
    if ((t & 63) == 0) red[t >> 6] = partial;
    __syncthreads();
    if (t == 0) {
        bsum[sem] = red[0] + red[1] + red[2] + red[3];
    }
}

static __global__ __launch_bounds__(256) void ssim_reduce(
    const float* __restrict__ bsum, float* __restrict__ out)
{
    __shared__ double red[4];
    const int t = threadIdx.x;
    double s = 0.0;
    for (int i = t; i < NBLK; i += 256) s += (double)bsum[i];
    #pragma unroll
    for (int off = 32; off >= 1; off >>= 1)
        s += __shfl_down(s, off, 64);
    if ((t & 63) == 0) red[t >> 6] = s;
    __syncthreads();
    if (t == 0) {
        const double tot = red[0] + red[1] + red[2] + red[3];
        out[0] = (float)(tot / (double)((long)NB * DOUT * HOUT * WOUT));
    }
}

extern "C" void kernel_launch(void* const* d_in, const int* in_sizes, int n_in,
                              void* d_out, int out_size, void* d_ws, size_t ws_size,
                              hipStream_t stream)
{
    const float* img1 = (const float*)d_in[0];
    const float* img2 = (const float*)d_in[1];
    const float* win  = (const float*)d_in[2];
    float* out  = (float*)d_out;
    float* bsum = (float*)d_ws;   // 1536 floats = 6 KB scratch

    dim3 grid(16, 16, NB * DCH);
    ssim_main<<<grid, 256, 0, stream>>>(img1, img2, win, bsum);
    ssim_reduce<<<1, 256, 0, stream>>>(bsum, out);
}